// Round 5
// baseline (290.875 us; speedup 1.0000x reference)
//
#include <hip/hip_runtime.h>
#include <math.h>

// Problem dims (fixed by reference)
constexpr int cB = 8, cH = 512, cL = 4096, cN = 32;
constexpr int cG = 32, cLC = 128;            // 32 chunks of 128 along L
constexpr int cHN = cH * cN;                 // 16384

// Workspace layout (float offsets)
constexpr size_t OF_RR  = 0;
constexpr size_t OF_RI  = (size_t)cHN;
constexpr size_t OF_RPR = (size_t)2*cHN;     // r^128
constexpr size_t OF_RPI = (size_t)3*cHN;
constexpr size_t OF_C2R = (size_t)4*cHN;     // 2*Cs
constexpr size_t OF_C2I = (size_t)5*cHN;
constexpr size_t OF_DR  = (size_t)6*cHN;     // dt*Ar
constexpr size_t OF_DI  = (size_t)7*cHN;     // dt*Ai
constexpr size_t OF_K   = (size_t)8*cHN;                  // (unused; layout stability)
constexpr size_t OF_WP  = OF_K + (size_t)512*128;         // bf16 W packed: 1024*512 ush
constexpr size_t OF_A   = OF_WP + (size_t)1024*512/2;     // bf16 A=[T|Er|-Ei]: [512][128][192] ush
constexpr size_t OF_V   = OF_A + (size_t)512*128*192/2;   // bf16 V: [512][64][128] ush
constexpr size_t OF_XP  = OF_V + (size_t)512*64*128/2;    // bf16 states: [512][256][64] ush
constexpr size_t OF_G   = OF_XP + (size_t)512*256*64/2;   // bf16 g: [B][H][L] ush
// OF_G doubles as u_bf[b][h][l] between k_state_gemm and k_conv: conv block h
// reads rows (b,h,:) before its first barrier and overwrites the same rows with
// g after it — safe aliasing, zero extra workspace.
// gT (bf16 [B][L][H] = 33.55 MB) ALIASES [OF_A, OF_XP) (dead after k_conv).
constexpr size_t OF_GT  = OF_A;
// end = OF_G + 8388608 = 21,430,272 floats = 85.7 MB (unchanged)

typedef __bf16 bf16x8 __attribute__((ext_vector_type(8)));
typedef float  f32x4  __attribute__((ext_vector_type(4)));

static __device__ __forceinline__ ushort f2bf(float x) {
    unsigned u = __float_as_uint(x);
    unsigned r = (u + 0x7fffu + ((u >> 16) & 1u)) >> 16;   // RNE
    return (ushort)r;
}
static __device__ __forceinline__ float bf2f(ushort v) {
    return __uint_as_float(((unsigned)v) << 16);
}
static __device__ __forceinline__ unsigned pk2(float a, float b) {
    return (unsigned)f2bf(a) | ((unsigned)f2bf(b) << 16);
}
static __device__ __forceinline__ float gelu(float v) {
    return 0.5f * v * (1.0f + erff(v * 0.70710678118654752f));
}
static __device__ __forceinline__ void gload16(const void* g, void* l) {
    __builtin_amdgcn_global_load_lds(
        (const __attribute__((address_space(1))) unsigned*)g,
        (__attribute__((address_space(3))) unsigned*)l, 16, 0, 0);
}

// ---------------- K0: per-(h,n) constants + V matrix (fused) ----------------
__global__ void k_consts_vmat(const float* __restrict__ log_dt,
                              const float* __restrict__ log_A_real,
                              const float* __restrict__ A_imag,
                              const float* __restrict__ Cin,
                              float* __restrict__ ws,
                              ushort* __restrict__ wsu)
{
    int tid = blockIdx.x * 256 + threadIdx.x;
    if (tid >= cHN) return;
    int h = tid >> 5, n = tid & 31;
    float dt = expf(log_dt[h]);
    float Ar = -expf(log_A_real[tid]);
    float Ai = A_imag[tid];
    float dr = dt * Ar, di = dt * Ai;
    float er = expf(dr);
    float rr = er * cosf(di), ri = er * sinf(di);
    float erL = expf(dr * (float)cLC);
    float diL = di * (float)cLC;
    float rpr = erL * cosf(diL), rpi = erL * sinf(diL);
    float cr = Cin[2*tid], ci = Cin[2*tid+1];
    float nr = rr - 1.0f, ni = ri;
    float inv = 1.0f / (Ar*Ar + Ai*Ai);
    float wr = (nr*Ar + ni*Ai) * inv;
    float wi = (ni*Ar - nr*Ai) * inv;
    float csr = cr*wr - ci*wi;
    float csi = cr*wi + ci*wr;
    ws[OF_RR  + tid] = rr;  ws[OF_RI  + tid] = ri;
    ws[OF_RPR + tid] = rpr; ws[OF_RPI + tid] = rpi;
    ws[OF_C2R + tid] = 2.0f*csr; ws[OF_C2I + tid] = 2.0f*csi;
    ws[OF_DR  + tid] = dr;  ws[OF_DI  + tid] = di;

    // --- vmat body (fused): powers r^(127-j) ---
    float e127 = expf(dr * 127.f), a127 = di * 127.f;
    float pr = e127 * cosf(a127), pi_ = e127 * sinf(a127);
    float rie = expf(-dr);
    float rc = rie * cosf(di), rs = -rie * sinf(di);
    ushort* vre = wsu + 2*OF_V + ((size_t)h*64 + n) * 128;
    ushort* vim = wsu + 2*OF_V + ((size_t)h*64 + 32 + n) * 128;
    for (int j4 = 0; j4 < 128; j4 += 4) {
        ushort4 r4, i4;
        #pragma unroll
        for (int e = 0; e < 4; ++e) {
            ((ushort*)&r4)[e] = f2bf(pr);
            ((ushort*)&i4)[e] = f2bf(pi_);
            float npr = pr*rc - pi_*rs;
            float npi = pr*rs + pi_*rc;
            pr = npr; pi_ = npi;
        }
        *(ushort4*)&vre[j4] = r4;
        *(ushort4*)&vim[j4] = i4;
    }
}

// ---------------- K0b: pack W -> bf16 with GLU row interleave ----------------
__global__ void k_pack_w(const float* __restrict__ W, ushort* __restrict__ Wp)
{
    int idx = blockIdx.x * 256 + threadIdx.x;
    int base = idx * 4;
    int m = base >> 9;
    int k = base & 511;
    int src = (m & 1) ? (512 + (m >> 1)) : (m >> 1);
    float4 v = *(const float4*)&W[(size_t)src * 512 + k];
    ushort4 o;
    o.x = f2bf(v.x); o.y = f2bf(v.y); o.z = f2bf(v.z); o.w = f2bf(v.w);
    *(ushort4*)&Wp[base] = o;
}

// ---------------- E matrix + k vector + Toeplitz fill (fused via LDS) ----------------
__global__ void k_embt(const float* __restrict__ ws, const float* __restrict__ Dvec,
                       ushort* __restrict__ wsu)
{
    __shared__ float kv[256];
    int t = threadIdx.x;
    int tid = blockIdx.x * 256 + t;             // 65536
    int h = tid >> 7, l = tid & 127;
    float fl = (float)l, fl1 = (float)(l + 1);
    const float* dr_ = ws + OF_DR + (size_t)h*32;
    const float* di_ = ws + OF_DI + (size_t)h*32;
    const float* c2r_ = ws + OF_C2R + (size_t)h*32;
    const float* c2i_ = ws + OF_C2I + (size_t)h*32;
    ushort* rowA = wsu + 2*OF_A + ((size_t)h*128 + l) * 192;
    float kacc = 0.f;
    for (int n4 = 0; n4 < 32; n4 += 4) {
        ushort4 prq, npq;
        #pragma unroll
        for (int e = 0; e < 4; ++e) {
            int n = n4 + e;
            float dr = dr_[n], di = di_[n], c2r = c2r_[n], c2i = c2i_[n];
            float e0 = expf(dr * fl), a0 = di * fl;
            float c0 = cosf(a0), s0 = sinf(a0);
            kacc += e0 * (c2r*c0 - c2i*s0);
            float e1 = expf(dr * fl1), a1 = di * fl1;
            float c1 = cosf(a1), s1 = sinf(a1);
            ((ushort*)&prq)[e] = f2bf(e1 * (c2r*c1 - c2i*s1));
            ((ushort*)&npq)[e] = f2bf(-e1 * (c2r*s1 + c2i*c1));
        }
        *(ushort4*)&rowA[128 + n4] = prq;
        *(ushort4*)&rowA[160 + n4] = npq;
    }
    kv[t] = kacc;
    __syncthreads();
    const float* krow = kv + ((t >> 7) << 7);
    float Dh = Dvec[h];
    for (int j8 = 0; j8 < 128; j8 += 8) {
        uint4 q;
        unsigned w[4];
        #pragma unroll
        for (int p = 0; p < 4; ++p) {
            int j0 = j8 + 2*p, j1 = j0 + 1;
            float v0 = (j0 <= l) ? krow[l - j0] : 0.f;
            float v1 = (j1 <= l) ? krow[l - j1] : 0.f;
            if (j0 == l) v0 += Dh;
            if (j1 == l) v1 += Dh;
            w[p] = pk2(v0, v1);
        }
        q.x = w[0]; q.y = w[1]; q.z = w[2]; q.w = w[3];
        *(uint4*)&rowA[j8] = q;
    }
}

// ---------------- State GEMM (+ streams bf16 u to OF_G as u_bf[b][h][l]) ----------------
__global__ __launch_bounds__(256) void k_state_gemm(const float* __restrict__ u,
                                                    const ushort* __restrict__ wsu,
                                                    ushort* __restrict__ xp,
                                                    ushort* __restrict__ ubf)
{
    __shared__ ushort Vs[64 * 136];
    __shared__ ushort Bs[256 * 40];
    const int t = threadIdx.x;
    const int h = blockIdx.x;
    const int wn = t >> 6, lane = t & 63;
    const int lm = lane & 15, q = lane >> 4;

    {   // stage V[h] whole: 64x128 bf16
        int idx = t * 32;
        int row = idx >> 7, kk = idx & 127;
        const ushort* src = wsu + 2*OF_V + ((size_t)h*64 + row) * 128 + kk;
        uint4 v0 = *(const uint4*)&src[0],  v1 = *(const uint4*)&src[8];
        uint4 v2 = *(const uint4*)&src[16], v3 = *(const uint4*)&src[24];
        ushort* d = (ushort*)Vs + row * 136 + kk;
        *(uint4*)&d[0] = v0; *(uint4*)&d[8] = v1;
        *(uint4*)&d[16] = v2; *(uint4*)&d[24] = v3;
    }

    const int b = t >> 5, c = t & 31;
    f32x4 acc[4][4];
    #pragma unroll
    for (int i = 0; i < 4; ++i)
        #pragma unroll
        for (int j = 0; j < 4; ++j) acc[i][j] = (f32x4){0.f,0.f,0.f,0.f};

    for (int k0 = 0; k0 < 128; k0 += 32) {
        const float* up = u + ((size_t)(b*cH + h)) * cL + (size_t)c*128 + k0;
        float4 f[8];
        #pragma unroll
        for (int e = 0; e < 8; ++e) f[e] = *(const float4*)&up[4*e];
        uint4 w[4];
        #pragma unroll
        for (int e = 0; e < 4; ++e) {
            w[e].x = pk2(f[2*e].x, f[2*e].y);     w[e].y = pk2(f[2*e].z, f[2*e].w);
            w[e].z = pk2(f[2*e+1].x, f[2*e+1].y); w[e].w = pk2(f[2*e+1].z, f[2*e+1].w);
        }
        // stream bf16 u to OF_G (consumed by k_conv, then overwritten by g)
        {
            ushort* ub_row = ubf + ((size_t)(b*cH + h)) * cL + (size_t)c*128 + k0;
            #pragma unroll
            for (int e = 0; e < 4; ++e)
                *(uint4*)&ub_row[8*e] = w[e];
        }
        __syncthreads();
        ushort* d = (ushort*)Bs + t * 40;
        #pragma unroll
        for (int e = 0; e < 4; ++e)
            *(uint4*)&d[8*e] = w[e];
        __syncthreads();
        bf16x8 af[4], bfr[4];
        #pragma unroll
        for (int mi = 0; mi < 4; ++mi)
            af[mi] = *(const bf16x8*)&Vs[(16*mi + lm) * 136 + k0 + 8*q];
        #pragma unroll
        for (int ni = 0; ni < 4; ++ni)
            bfr[ni] = *(const bf16x8*)&Bs[(64*wn + 16*ni + lm) * 40 + 8*q];
        #pragma unroll
        for (int mi = 0; mi < 4; ++mi)
            #pragma unroll
            for (int ni = 0; ni < 4; ++ni)
                acc[mi][ni] = __builtin_amdgcn_mfma_f32_16x16x32_bf16(af[mi], bfr[ni], acc[mi][ni], 0,0,0);
    }
    #pragma unroll
    for (int mi = 0; mi < 4; ++mi)
        #pragma unroll
        for (int ni = 0; ni < 4; ++ni) {
            int col = 64*wn + 16*ni + lm;
            int comp = 16*mi + 4*q;
            ushort4 st;
            st.x = f2bf(acc[mi][ni][0]); st.y = f2bf(acc[mi][ni][1]);
            st.z = f2bf(acc[mi][ni][2]); st.w = f2bf(acc[mi][ni][3]);
            *(ushort4*)&xp[((size_t)h*256 + col) * 64 + comp] = st;
        }
}

// ---------------- Conv GEMM v3: one block per h, 512 thr; scan fused in LDS ----------------
// C[l][gc] = sum_k A[h][l][k] * B[gc][k];  B = [u_bf16 | Xr | Xi] per gc=(b,chunk).
// u comes pre-packed bf16 from k_state_gemm (OF_G region); the chunk-scan
// (formerly k_scan2) runs in LDS between staging and MFMA: thread (b,n) walks
// c=0..31 replacing raw chunk-sums s[c] with exclusive-prefix states X[c].
__global__ __launch_bounds__(512) void k_conv(const ushort* ubf,
                                              const float* __restrict__ ws,
                                              const ushort* __restrict__ wsu,
                                              ushort* g)
{
    __shared__ ushort As[128 * 200];   // 51200 B
    __shared__ ushort Bs[256 * 200];   // 102400 B  (total 150 KB)
    const int t = threadIdx.x;
    const int h = blockIdx.x;
    const int wave = t >> 6, lane = t & 63;
    const int wm = wave & 1, wn = wave >> 1;   // 2 M-halves x 4 N-quarters
    const int lm = lane & 15, q = lane >> 4;

    // --- stage A: 128 rows x 192 k (4 threads/row, 48 ush each) ---
    {
        const int row = t >> 2, c0 = (t & 3) * 48;
        const ushort* Ab = wsu + 2*OF_A + ((size_t)h*128 + row) * 192 + c0;
        ushort* d = &As[row * 200 + c0];
        #pragma unroll
        for (int e = 0; e < 6; ++e)
            *(uint4*)&d[8*e] = *(const uint4*)&Ab[8*e];
    }
    // --- stage B: 256 gc x (128 u_bf | 64 xp) (2 threads/gc) ---
    {
        const int gc = t >> 1, half = t & 1;
        const int ub = gc >> 5, uc = gc & 31;
        const ushort* up = ubf + ((size_t)(ub*cH + h)) * cL + (size_t)uc*128 + half*64;
        ushort* d = &Bs[gc * 200 + half*64];
        #pragma unroll
        for (int e = 0; e < 8; ++e)
            *(uint4*)&d[8*e] = *(const uint4*)&up[8*e];
        const ushort* xs = wsu + 2*OF_XP + ((size_t)h*256 + gc) * 64 + half*32;
        ushort* dx = &Bs[gc * 200 + 128 + half*32];
        #pragma unroll
        for (int e = 0; e < 4; ++e)
            *(uint4*)&dx[8*e] = *(const uint4*)&xs[8*e];
    }
    __syncthreads();

    // --- fused scan (was k_scan2): thread (b,n) walks 32 chunks in LDS ---
    if (t < 256) {
        const int sb = t >> 5, sn = t & 31;
        float rpr = ws[OF_RPR + (size_t)h*32 + sn];
        float rpi = ws[OF_RPI + (size_t)h*32 + sn];
        float Xr = 0.f, Xi = 0.f;
        ushort* p = &Bs[(sb*32) * 200 + 128 + sn];
        #pragma unroll 4
        for (int c = 0; c < cG; ++c, p += 200) {
            float sr = bf2f(p[0]), si = bf2f(p[32]);
            p[0]  = f2bf(Xr);
            p[32] = f2bf(Xi);
            float nXr = fmaf(rpr, Xr, fmaf(-rpi, Xi, sr));
            float nXi = fmaf(rpr, Xi, fmaf(rpi, Xr, si));
            Xr = nXr; Xi = nXi;
        }
    }
    __syncthreads();

    f32x4 acc[4][4];
    #pragma unroll
    for (int i = 0; i < 4; ++i)
        #pragma unroll
        for (int j = 0; j < 4; ++j) acc[i][j] = (f32x4){0.f,0.f,0.f,0.f};

    #pragma unroll
    for (int k0 = 0; k0 < 192; k0 += 32) {
        // lower-triangular skip: rows 0..63 x k 64..127 are all zero
        if ((wm == 0) && (k0 == 64 || k0 == 96)) continue;
        bf16x8 af[4], bfr[4];
        #pragma unroll
        for (int mi = 0; mi < 4; ++mi)
            af[mi] = *(const bf16x8*)&As[(64*wm + 16*mi + lm) * 200 + k0 + 8*q];
        #pragma unroll
        for (int ni = 0; ni < 4; ++ni)
            bfr[ni] = *(const bf16x8*)&Bs[(64*wn + 16*ni + lm) * 200 + k0 + 8*q];
        #pragma unroll
        for (int mi = 0; mi < 4; ++mi)
            #pragma unroll
            for (int ni = 0; ni < 4; ++ni)
                acc[mi][ni] = __builtin_amdgcn_mfma_f32_16x16x32_bf16(af[mi], bfr[ni], acc[mi][ni], 0,0,0);
    }
    // epilogue: gelu -> bf16 g[b][h][oc*128 + l]  (overwrites the u_bf rows read above)
    #pragma unroll
    for (int ni = 0; ni < 4; ++ni) {
        int gc = 64*wn + 16*ni + lm;
        int ob = gc >> 5, oc = gc & 31;
        ushort* grow = g + ((size_t)(ob*cH + h)) * cL + (size_t)oc*128;
        #pragma unroll
        for (int mi = 0; mi < 4; ++mi) {
            int l = 64*wm + 16*mi + 4*q;
            ushort4 st;
            st.x = f2bf(gelu(acc[mi][ni][0]));
            st.y = f2bf(gelu(acc[mi][ni][1]));
            st.z = f2bf(gelu(acc[mi][ni][2]));
            st.w = f2bf(gelu(acc[mi][ni][3]));
            *(ushort4*)&grow[l] = st;
        }
    }
}

// ---------------- transpose g[b][h][l] -> gT[b][l][h] (bf16) ----------------
__global__ __launch_bounds__(256) void k_transpose(const ushort* __restrict__ gsrc,
                                                   ushort* __restrict__ gT)
{
    __shared__ ushort tile[64 * 64];
    const int t = threadIdx.x;
    const int b  = blockIdx.z;
    const int h0 = blockIdx.y << 6;
    const int l0 = blockIdx.x << 6;
    const ushort* gb = gsrc + ((size_t)b * cH + h0) * cL + l0;
    const int lb = t & 7;
    #pragma unroll
    for (int half = 0; half < 2; ++half) {
        int r = (t >> 3) + half * 32;
        uint4 v = *(const uint4*)&gb[(size_t)r * cL + lb * 8];
        int sb = lb ^ (r & 7) ^ (r >> 3);
        *(uint4*)&tile[r * 64 + sb * 8] = v;
    }
    __syncthreads();
    ushort* gTb = gT + ((size_t)b * cL + l0) * cH + h0;
    #pragma unroll
    for (int half = 0; half < 2; ++half) {
        int l  = (t >> 3) + half * 32;
        int hb = t & 7;
        ushort vals[8];
        #pragma unroll
        for (int e = 0; e < 8; ++e) {
            int r  = hb * 8 + e;
            int sb = (l >> 3) ^ (r & 7) ^ (r >> 3);
            vals[e] = tile[r * 64 + sb * 8 + (l & 7)];
        }
        *(uint4*)&gTb[(size_t)l * cH + hb * 8] = *(uint4*)vals;
    }
}

// ---------------- K4: B^T GEMM, 2-buffer m97 structure (R1 winner) ----------------
__global__ __launch_bounds__(256) void k_gemm2(const ushort* __restrict__ Wp,
                                               const float* __restrict__ bias,
                                               const ushort* __restrict__ gT,
                                               float* __restrict__ out)
{
    __shared__ ushort As[2][128 * 32];
    __shared__ ushort Bs[2][128 * 32];
    const int t    = threadIdx.x;
    const int l0   = blockIdx.x * 128;
    const int by   = blockIdx.y;
    const int b    = blockIdx.z;
    const int wave = t >> 6, lane = t & 63;
    const int wm   = wave & 1, wn = wave >> 1;
    const int lm   = lane & 15, q = lane >> 4;

    const int srow = lane >> 2;              // row within 16-row chunk
    const int scol = (lane & 3) * 8;         // ushort offset within 64-B row
    const ushort* Ag = Wp + (size_t)(by * 128) * 512;
    const ushort* Bg = gT + ((size_t)b * cL + l0) * 512;

    f32x4 acc[4][4];
    #pragma unroll
    for (int i = 0; i < 4; ++i)
        #pragma unroll
        for (int j = 0; j < 4; ++j)
            acc[i][j] = (f32x4){0.f, 0.f, 0.f, 0.f};

    auto stage = [&](ushort* Asb, ushort* Bsb, int k0) {
        #pragma unroll
        for (int j = 0; j < 2; ++j) {
            int row = 32*wave + 16*j + srow;
            gload16(Ag + (size_t)row * 512 + k0 + scol,
                    (char*)Asb + wave*2048 + j*1024);
            gload16(Bg + (size_t)row * 512 + k0 + scol,
                    (char*)Bsb + wave*2048 + j*1024);
        }
    };
    auto compute = [&](const ushort* Asb, const ushort* Bsb) {
        bf16x8 af[4], bfr[4];
        #pragma unroll
        for (int mi = 0; mi < 4; ++mi)
            af[mi] = *(const bf16x8*)&Asb[(64*wm + 16*mi + lm) * 32 + 8*q];
        #pragma unroll
        for (int ni = 0; ni < 4; ++ni)
            bfr[ni] = *(const bf16x8*)&Bsb[(64*wn + 16*ni + lm) * 32 + 8*q];
        #pragma unroll
        for (int mi = 0; mi < 4; ++mi)
            #pragma unroll
            for (int ni = 0; ni < 4; ++ni)
                acc[mi][ni] = __builtin_amdgcn_mfma_f32_16x16x32_bf16(af[mi], bfr[ni], acc[mi][ni], 0,0,0);
    };

    stage(As[0], Bs[0], 0);
    __syncthreads();                         // drains vmcnt(0) -> buf0 ready
    int cur = 0;
    for (int ks = 0; ks < 15; ++ks) {
        stage(As[cur ^ 1], Bs[cur ^ 1], (ks + 1) * 32);   // prefetch next tile
        compute(As[cur], Bs[cur]);                         // MFMA current tile
        __syncthreads();                                   // drain prefetch + sync
        cur ^= 1;
    }
    compute(As[cur], Bs[cur]);

    // epilogue: bias + GLU
    const int obase = by * 64 + 32 * wm;
    #pragma unroll
    for (int mi = 0; mi < 4; ++mi) {
        #pragma unroll
        for (int p = 0; p < 2; ++p) {
            int o = obase + 8*mi + 2*q + p;
            float ba = bias[o], bb = bias[512 + o];
            float* orow = out + ((size_t)b * cH + o) * cL + l0 + 64*wn + lm;
            #pragma unroll
            for (int ni = 0; ni < 4; ++ni) {
                float av = acc[mi][ni][2*p]     + ba;
                float gv = acc[mi][ni][2*p + 1] + bb;
                orow[16 * ni] = av / (1.f + expf(-gv));
            }
        }
    }
}

extern "C" void kernel_launch(void* const* d_in, const int* in_sizes, int n_in,
                              void* d_out, int out_size, void* d_ws, size_t ws_size,
                              hipStream_t stream)
{
    (void)in_sizes; (void)n_in; (void)out_size; (void)ws_size;
    const float* u          = (const float*)d_in[0];
    const float* log_dt     = (const float*)d_in[1];
    const float* log_A_real = (const float*)d_in[2];
    const float* A_imag     = (const float*)d_in[3];
    const float* C          = (const float*)d_in[4];
    const float* D          = (const float*)d_in[5];
    const float* W          = (const float*)d_in[6];
    const float* bias       = (const float*)d_in[7];
    float* out = (float*)d_out;
    float* ws  = (float*)d_ws;
    ushort* wsu = (ushort*)d_ws;
    ushort* Wp  = wsu + 2*OF_WP;
    ushort* xp  = wsu + 2*OF_XP;
    ushort* gbf = wsu + 2*OF_G;    // u_bf before k_conv, g after
    ushort* gTu = wsu + 2*OF_GT;   // aliases A+V (dead after k_conv)

    hipLaunchKernelGGL(k_consts_vmat, dim3(cHN/256), dim3(256), 0, stream,
                       log_dt, log_A_real, A_imag, C, ws, wsu);
    hipLaunchKernelGGL(k_pack_w, dim3(1024*512/4/256), dim3(256), 0, stream, W, Wp);
    hipLaunchKernelGGL(k_embt, dim3(512*128/256), dim3(256), 0, stream, ws, D, wsu);
    hipLaunchKernelGGL(k_state_gemm, dim3(512), dim3(256), 0, stream, u, wsu, xp, gbf);
    hipLaunchKernelGGL(k_conv, dim3(512), dim3(512), 0, stream, gbf, ws, wsu, gbf);
    hipLaunchKernelGGL(k_transpose, dim3(cL/64, cH/64, cB), dim3(256), 0, stream, gbf, gTu);
    hipLaunchKernelGGL(k_gemm2, dim3(cL/128, 1024/128, cB), dim3(256), 0, stream,
                       Wp, bias, gTu, out);
}

// Round 6
// 267.220 us; speedup vs baseline: 1.0885x; 1.0885x over previous
//
#include <hip/hip_runtime.h>
#include <math.h>

// Problem dims (fixed by reference)
constexpr int cB = 8, cH = 512, cL = 4096, cN = 32;
constexpr int cG = 32, cLC = 128;            // 32 chunks of 128 along L
constexpr int cHN = cH * cN;                 // 16384

// Workspace layout (float offsets)
constexpr size_t OF_RR  = 0;
constexpr size_t OF_RI  = (size_t)cHN;
constexpr size_t OF_RPR = (size_t)2*cHN;     // r^128
constexpr size_t OF_RPI = (size_t)3*cHN;
constexpr size_t OF_C2R = (size_t)4*cHN;     // 2*Cs
constexpr size_t OF_C2I = (size_t)5*cHN;
constexpr size_t OF_DR  = (size_t)6*cHN;     // dt*Ar
constexpr size_t OF_DI  = (size_t)7*cHN;     // dt*Ai
constexpr size_t OF_K   = (size_t)8*cHN;                  // (unused; layout stability)
constexpr size_t OF_WP  = OF_K + (size_t)512*128;         // bf16 W packed: 1024*512 ush
constexpr size_t OF_A   = OF_WP + (size_t)1024*512/2;     // bf16 A=[T|Er|-Ei]: [512][128][192] ush
constexpr size_t OF_V   = OF_A + (size_t)512*128*192/2;   // bf16 V: [512][64][128] ush
constexpr size_t OF_XP  = OF_V + (size_t)512*64*128/2;    // (now unused; layout stability)
constexpr size_t OF_G   = OF_XP + (size_t)512*256*64/2;   // bf16 g: [B][H][L] ush
// gT (bf16 [B][L][H] = 33.55 MB) ALIASES [OF_A, OF_XP) (dead after k_conv).
constexpr size_t OF_GT  = OF_A;
// end = OF_G + 8388608 = 21,430,272 floats = 85.7 MB (unchanged)

typedef __bf16 bf16x8 __attribute__((ext_vector_type(8)));
typedef float  f32x4  __attribute__((ext_vector_type(4)));

static __device__ __forceinline__ ushort f2bf(float x) {
    unsigned u = __float_as_uint(x);
    unsigned r = (u + 0x7fffu + ((u >> 16) & 1u)) >> 16;   // RNE
    return (ushort)r;
}
static __device__ __forceinline__ float bf2f(ushort v) {
    return __uint_as_float(((unsigned)v) << 16);
}
static __device__ __forceinline__ unsigned pk2(float a, float b) {
    return (unsigned)f2bf(a) | ((unsigned)f2bf(b) << 16);
}
static __device__ __forceinline__ float gelu(float v) {
    return 0.5f * v * (1.0f + erff(v * 0.70710678118654752f));
}
static __device__ __forceinline__ void gload16(const void* g, void* l) {
    __builtin_amdgcn_global_load_lds(
        (const __attribute__((address_space(1))) unsigned*)g,
        (__attribute__((address_space(3))) unsigned*)l, 16, 0, 0);
}

// ---------------- K0: per-(h,n) constants + V matrix (fused) ----------------
__global__ void k_consts_vmat(const float* __restrict__ log_dt,
                              const float* __restrict__ log_A_real,
                              const float* __restrict__ A_imag,
                              const float* __restrict__ Cin,
                              float* __restrict__ ws,
                              ushort* __restrict__ wsu)
{
    int tid = blockIdx.x * 256 + threadIdx.x;
    if (tid >= cHN) return;
    int h = tid >> 5, n = tid & 31;
    float dt = expf(log_dt[h]);
    float Ar = -expf(log_A_real[tid]);
    float Ai = A_imag[tid];
    float dr = dt * Ar, di = dt * Ai;
    float er = expf(dr);
    float rr = er * cosf(di), ri = er * sinf(di);
    float erL = expf(dr * (float)cLC);
    float diL = di * (float)cLC;
    float rpr = erL * cosf(diL), rpi = erL * sinf(diL);
    float cr = Cin[2*tid], ci = Cin[2*tid+1];
    float nr = rr - 1.0f, ni = ri;
    float inv = 1.0f / (Ar*Ar + Ai*Ai);
    float wr = (nr*Ar + ni*Ai) * inv;
    float wi = (ni*Ar - nr*Ai) * inv;
    float csr = cr*wr - ci*wi;
    float csi = cr*wi + ci*wr;
    ws[OF_RR  + tid] = rr;  ws[OF_RI  + tid] = ri;
    ws[OF_RPR + tid] = rpr; ws[OF_RPI + tid] = rpi;
    ws[OF_C2R + tid] = 2.0f*csr; ws[OF_C2I + tid] = 2.0f*csi;
    ws[OF_DR  + tid] = dr;  ws[OF_DI  + tid] = di;

    // --- vmat body (fused): powers r^(127-j) ---
    float e127 = expf(dr * 127.f), a127 = di * 127.f;
    float pr = e127 * cosf(a127), pi_ = e127 * sinf(a127);
    float rie = expf(-dr);
    float rc = rie * cosf(di), rs = -rie * sinf(di);
    ushort* vre = wsu + 2*OF_V + ((size_t)h*64 + n) * 128;
    ushort* vim = wsu + 2*OF_V + ((size_t)h*64 + 32 + n) * 128;
    for (int j4 = 0; j4 < 128; j4 += 4) {
        ushort4 r4, i4;
        #pragma unroll
        for (int e = 0; e < 4; ++e) {
            ((ushort*)&r4)[e] = f2bf(pr);
            ((ushort*)&i4)[e] = f2bf(pi_);
            float npr = pr*rc - pi_*rs;
            float npi = pr*rs + pi_*rc;
            pr = npr; pi_ = npi;
        }
        *(ushort4*)&vre[j4] = r4;
        *(ushort4*)&vim[j4] = i4;
    }
}

// ---------------- K0b: pack W -> bf16 with GLU row interleave ----------------
__global__ void k_pack_w(const float* __restrict__ W, ushort* __restrict__ Wp)
{
    int idx = blockIdx.x * 256 + threadIdx.x;
    int base = idx * 4;
    int m = base >> 9;
    int k = base & 511;
    int src = (m & 1) ? (512 + (m >> 1)) : (m >> 1);
    float4 v = *(const float4*)&W[(size_t)src * 512 + k];
    ushort4 o;
    o.x = f2bf(v.x); o.y = f2bf(v.y); o.z = f2bf(v.z); o.w = f2bf(v.w);
    *(ushort4*)&Wp[base] = o;
}

// ---------------- E matrix + k vector + Toeplitz fill (fused via LDS) ----------------
__global__ void k_embt(const float* __restrict__ ws, const float* __restrict__ Dvec,
                       ushort* __restrict__ wsu)
{
    __shared__ float kv[256];
    int t = threadIdx.x;
    int tid = blockIdx.x * 256 + t;             // 65536
    int h = tid >> 7, l = tid & 127;
    float fl = (float)l, fl1 = (float)(l + 1);
    const float* dr_ = ws + OF_DR + (size_t)h*32;
    const float* di_ = ws + OF_DI + (size_t)h*32;
    const float* c2r_ = ws + OF_C2R + (size_t)h*32;
    const float* c2i_ = ws + OF_C2I + (size_t)h*32;
    ushort* rowA = wsu + 2*OF_A + ((size_t)h*128 + l) * 192;
    float kacc = 0.f;
    for (int n4 = 0; n4 < 32; n4 += 4) {
        ushort4 prq, npq;
        #pragma unroll
        for (int e = 0; e < 4; ++e) {
            int n = n4 + e;
            float dr = dr_[n], di = di_[n], c2r = c2r_[n], c2i = c2i_[n];
            float e0 = expf(dr * fl), a0 = di * fl;
            float c0 = cosf(a0), s0 = sinf(a0);
            kacc += e0 * (c2r*c0 - c2i*s0);
            float e1 = expf(dr * fl1), a1 = di * fl1;
            float c1 = cosf(a1), s1 = sinf(a1);
            ((ushort*)&prq)[e] = f2bf(e1 * (c2r*c1 - c2i*s1));
            ((ushort*)&npq)[e] = f2bf(-e1 * (c2r*s1 + c2i*c1));
        }
        *(ushort4*)&rowA[128 + n4] = prq;
        *(ushort4*)&rowA[160 + n4] = npq;
    }
    kv[t] = kacc;
    __syncthreads();
    const float* krow = kv + ((t >> 7) << 7);
    float Dh = Dvec[h];
    for (int j8 = 0; j8 < 128; j8 += 8) {
        uint4 q;
        unsigned w[4];
        #pragma unroll
        for (int p = 0; p < 4; ++p) {
            int j0 = j8 + 2*p, j1 = j0 + 1;
            float v0 = (j0 <= l) ? krow[l - j0] : 0.f;
            float v1 = (j1 <= l) ? krow[l - j1] : 0.f;
            if (j0 == l) v0 += Dh;
            if (j1 == l) v1 += Dh;
            w[p] = pk2(v0, v1);
        }
        q.x = w[0]; q.y = w[1]; q.z = w[2]; q.w = w[3];
        *(uint4*)&rowA[j8] = q;
    }
}

// ---------------- Conv mega-kernel: state GEMM + scan + conv GEMM, one block per h ----------------
// Phase 1: stage u->bf16 into Bs[gc][0..127]; V[h] (64x128) into As rows 0..63;
//          issue A-matrix loads into regs (T14 async-split).
// Phase 3: state GEMM S[comp][gc] = sum_j V[comp][j]*u[gc][j] -> Bs[gc][128+comp].
// Phase 4: chunk-scan in LDS (thread (b,n) walks 32 chunks); ds_write A-matrix
//          into As (overwrites V, dead after phase 3).
// Phase 5: main GEMM C[l][gc] = sum_k A[l][k]*B[gc][k], gelu -> g.
// Replaces the former k_state_gemm + k_scan2 + k_conv (u read once, xp never
// leaves LDS: saves ~96 MB HBM + a launch).
__global__ __launch_bounds__(512) void k_conv(const float* __restrict__ u,
                                              const float* __restrict__ ws,
                                              const ushort* __restrict__ wsu,
                                              ushort* __restrict__ g)
{
    __shared__ ushort As[128 * 200];   // 51200 B: V (rows 0..63) then A-matrix
    __shared__ ushort Bs[256 * 200];   // 102400 B: [gc][u_bf 0..127 | states 128..191]
    const int t = threadIdx.x;
    const int h = blockIdx.x;
    const int wave = t >> 6, lane = t & 63;
    const int wm = wave & 1, wn = wave >> 1;   // main GEMM: 2 M-halves x 4 N-quarters
    const int lm = lane & 15, q = lane >> 4;

    // --- issue A-matrix global loads early; ds_write deferred to phase 4 ---
    uint4 areg[6];
    const int arow = t >> 2, ac0 = (t & 3) * 48;
    {
        const ushort* Ab = wsu + 2*OF_A + ((size_t)h*128 + arow) * 192 + ac0;
        #pragma unroll
        for (int e = 0; e < 6; ++e) areg[e] = *(const uint4*)&Ab[8*e];
    }
    // --- stage V[h]: 64x128 bf16 into As rows 0..63 (2 uint4/thread) ---
    {
        const int vrow = t >> 3, vc0 = (t & 7) * 16;
        const ushort* vs = wsu + 2*OF_V + ((size_t)h*64 + vrow) * 128 + vc0;
        uint4 v0 = *(const uint4*)&vs[0], v1 = *(const uint4*)&vs[8];
        *(uint4*)&As[vrow*200 + vc0]     = v0;
        *(uint4*)&As[vrow*200 + vc0 + 8] = v1;
    }
    // --- stage u (fp32 -> bf16): 256 gc x 128, 2 threads/gc ---
    {
        const int gc = t >> 1, half = t & 1;
        const int ub = gc >> 5, uc = gc & 31;
        const float* up = u + ((size_t)(ub*cH + h)) * cL + (size_t)uc*128 + half*64;
        ushort* d = &Bs[gc * 200 + half*64];
        #pragma unroll
        for (int e = 0; e < 8; ++e) {
            float4 f0 = *(const float4*)&up[8*e];
            float4 f1 = *(const float4*)&up[8*e + 4];
            uint4 w;
            w.x = pk2(f0.x, f0.y); w.y = pk2(f0.z, f0.w);
            w.z = pk2(f1.x, f1.y); w.w = pk2(f1.z, f1.w);
            *(uint4*)&d[8*e] = w;
        }
    }
    __syncthreads();

    // --- phase 3: state GEMM (was k_state_gemm). Per wave: 32 gc cols, all 64 comps ---
    {
        f32x4 accs[4][2];
        #pragma unroll
        for (int i = 0; i < 4; ++i)
            #pragma unroll
            for (int j = 0; j < 2; ++j) accs[i][j] = (f32x4){0.f,0.f,0.f,0.f};
        #pragma unroll
        for (int j0 = 0; j0 < 128; j0 += 32) {
            bf16x8 vf[4], uf[2];
            #pragma unroll
            for (int mi = 0; mi < 4; ++mi)
                vf[mi] = *(const bf16x8*)&As[(16*mi + lm) * 200 + j0 + 8*q];
            #pragma unroll
            for (int ni = 0; ni < 2; ++ni)
                uf[ni] = *(const bf16x8*)&Bs[(32*wave + 16*ni + lm) * 200 + j0 + 8*q];
            #pragma unroll
            for (int mi = 0; mi < 4; ++mi)
                #pragma unroll
                for (int ni = 0; ni < 2; ++ni)
                    accs[mi][ni] = __builtin_amdgcn_mfma_f32_16x16x32_bf16(vf[mi], uf[ni], accs[mi][ni], 0,0,0);
        }
        // write chunk-sums: comp = 16mi+4q+e, col = 32*wave+16ni+lm
        #pragma unroll
        for (int mi = 0; mi < 4; ++mi)
            #pragma unroll
            for (int ni = 0; ni < 2; ++ni) {
                int col = 32*wave + 16*ni + lm;
                ushort4 st;
                st.x = f2bf(accs[mi][ni][0]); st.y = f2bf(accs[mi][ni][1]);
                st.z = f2bf(accs[mi][ni][2]); st.w = f2bf(accs[mi][ni][3]);
                *(ushort4*)&Bs[col*200 + 128 + 16*mi + 4*q] = st;
            }
    }
    __syncthreads();

    // --- phase 4a: chunk scan (was k_scan2): thread (b,n) walks 32 chunks ---
    if (t < 256) {
        const int sb = t >> 5, sn = t & 31;
        float rpr = ws[OF_RPR + (size_t)h*32 + sn];
        float rpi = ws[OF_RPI + (size_t)h*32 + sn];
        float Xr = 0.f, Xi = 0.f;
        ushort* p = &Bs[(sb*32) * 200 + 128 + sn];
        #pragma unroll 4
        for (int c = 0; c < cG; ++c, p += 200) {
            float sr = bf2f(p[0]), si = bf2f(p[32]);
            p[0]  = f2bf(Xr);
            p[32] = f2bf(Xi);
            float nXr = fmaf(rpr, Xr, fmaf(-rpi, Xi, sr));
            float nXi = fmaf(rpr, Xi, fmaf(rpi, Xr, si));
            Xr = nXr; Xi = nXi;
        }
    }
    // --- phase 4b: ds_write A-matrix from regs (overwrites V) ---
    {
        ushort* d = &As[arow*200 + ac0];
        #pragma unroll
        for (int e = 0; e < 6; ++e) *(uint4*)&d[8*e] = areg[e];
    }
    __syncthreads();

    // --- phase 5: main GEMM over K=192 with lower-triangular skip ---
    f32x4 acc[4][4];
    #pragma unroll
    for (int i = 0; i < 4; ++i)
        #pragma unroll
        for (int j = 0; j < 4; ++j) acc[i][j] = (f32x4){0.f,0.f,0.f,0.f};

    #pragma unroll
    for (int k0 = 0; k0 < 192; k0 += 32) {
        if ((wm == 0) && (k0 == 64 || k0 == 96)) continue;
        bf16x8 af[4], bfr[4];
        #pragma unroll
        for (int mi = 0; mi < 4; ++mi)
            af[mi] = *(const bf16x8*)&As[(64*wm + 16*mi + lm) * 200 + k0 + 8*q];
        #pragma unroll
        for (int ni = 0; ni < 4; ++ni)
            bfr[ni] = *(const bf16x8*)&Bs[(64*wn + 16*ni + lm) * 200 + k0 + 8*q];
        #pragma unroll
        for (int mi = 0; mi < 4; ++mi)
            #pragma unroll
            for (int ni = 0; ni < 4; ++ni)
                acc[mi][ni] = __builtin_amdgcn_mfma_f32_16x16x32_bf16(af[mi], bfr[ni], acc[mi][ni], 0,0,0);
    }
    // epilogue: gelu -> bf16 g[b][h][oc*128 + l]
    #pragma unroll
    for (int ni = 0; ni < 4; ++ni) {
        int gc = 64*wn + 16*ni + lm;
        int ob = gc >> 5, oc = gc & 31;
        ushort* grow = g + ((size_t)(ob*cH + h)) * cL + (size_t)oc*128;
        #pragma unroll
        for (int mi = 0; mi < 4; ++mi) {
            int l = 64*wm + 16*mi + 4*q;
            ushort4 st;
            st.x = f2bf(gelu(acc[mi][ni][0]));
            st.y = f2bf(gelu(acc[mi][ni][1]));
            st.z = f2bf(gelu(acc[mi][ni][2]));
            st.w = f2bf(gelu(acc[mi][ni][3]));
            *(ushort4*)&grow[l] = st;
        }
    }
}

// ---------------- transpose g[b][h][l] -> gT[b][l][h] (bf16) ----------------
__global__ __launch_bounds__(256) void k_transpose(const ushort* __restrict__ gsrc,
                                                   ushort* __restrict__ gT)
{
    __shared__ ushort tile[64 * 64];
    const int t = threadIdx.x;
    const int b  = blockIdx.z;
    const int h0 = blockIdx.y << 6;
    const int l0 = blockIdx.x << 6;
    const ushort* gb = gsrc + ((size_t)b * cH + h0) * cL + l0;
    const int lb = t & 7;
    #pragma unroll
    for (int half = 0; half < 2; ++half) {
        int r = (t >> 3) + half * 32;
        uint4 v = *(const uint4*)&gb[(size_t)r * cL + lb * 8];
        int sb = lb ^ (r & 7) ^ (r >> 3);
        *(uint4*)&tile[r * 64 + sb * 8] = v;
    }
    __syncthreads();
    ushort* gTb = gT + ((size_t)b * cL + l0) * cH + h0;
    #pragma unroll
    for (int half = 0; half < 2; ++half) {
        int l  = (t >> 3) + half * 32;
        int hb = t & 7;
        ushort vals[8];
        #pragma unroll
        for (int e = 0; e < 8; ++e) {
            int r  = hb * 8 + e;
            int sb = (l >> 3) ^ (r & 7) ^ (r >> 3);
            vals[e] = tile[r * 64 + sb * 8 + (l & 7)];
        }
        *(uint4*)&gTb[(size_t)l * cH + hb * 8] = *(uint4*)vals;
    }
}

// ---------------- K4: B^T GEMM, 2-buffer m97 structure (R1 winner) ----------------
__global__ __launch_bounds__(256) void k_gemm2(const ushort* __restrict__ Wp,
                                               const float* __restrict__ bias,
                                               const ushort* __restrict__ gT,
                                               float* __restrict__ out)
{
    __shared__ ushort As[2][128 * 32];
    __shared__ ushort Bs[2][128 * 32];
    const int t    = threadIdx.x;
    const int l0   = blockIdx.x * 128;
    const int by   = blockIdx.y;
    const int b    = blockIdx.z;
    const int wave = t >> 6, lane = t & 63;
    const int wm   = wave & 1, wn = wave >> 1;
    const int lm   = lane & 15, q = lane >> 4;

    const int srow = lane >> 2;              // row within 16-row chunk
    const int scol = (lane & 3) * 8;         // ushort offset within 64-B row
    const ushort* Ag = Wp + (size_t)(by * 128) * 512;
    const ushort* Bg = gT + ((size_t)b * cL + l0) * 512;

    f32x4 acc[4][4];
    #pragma unroll
    for (int i = 0; i < 4; ++i)
        #pragma unroll
        for (int j = 0; j < 4; ++j)
            acc[i][j] = (f32x4){0.f, 0.f, 0.f, 0.f};

    auto stage = [&](ushort* Asb, ushort* Bsb, int k0) {
        #pragma unroll
        for (int j = 0; j < 2; ++j) {
            int row = 32*wave + 16*j + srow;
            gload16(Ag + (size_t)row * 512 + k0 + scol,
                    (char*)Asb + wave*2048 + j*1024);
            gload16(Bg + (size_t)row * 512 + k0 + scol,
                    (char*)Bsb + wave*2048 + j*1024);
        }
    };
    auto compute = [&](const ushort* Asb, const ushort* Bsb) {
        bf16x8 af[4], bfr[4];
        #pragma unroll
        for (int mi = 0; mi < 4; ++mi)
            af[mi] = *(const bf16x8*)&Asb[(64*wm + 16*mi + lm) * 32 + 8*q];
        #pragma unroll
        for (int ni = 0; ni < 4; ++ni)
            bfr[ni] = *(const bf16x8*)&Bsb[(64*wn + 16*ni + lm) * 32 + 8*q];
        #pragma unroll
        for (int mi = 0; mi < 4; ++mi)
            #pragma unroll
            for (int ni = 0; ni < 4; ++ni)
                acc[mi][ni] = __builtin_amdgcn_mfma_f32_16x16x32_bf16(af[mi], bfr[ni], acc[mi][ni], 0,0,0);
    };

    stage(As[0], Bs[0], 0);
    __syncthreads();                         // drains vmcnt(0) -> buf0 ready
    int cur = 0;
    for (int ks = 0; ks < 15; ++ks) {
        stage(As[cur ^ 1], Bs[cur ^ 1], (ks + 1) * 32);   // prefetch next tile
        compute(As[cur], Bs[cur]);                         // MFMA current tile
        __syncthreads();                                   // drain prefetch + sync
        cur ^= 1;
    }
    compute(As[cur], Bs[cur]);

    // epilogue: bias + GLU
    const int obase = by * 64 + 32 * wm;
    #pragma unroll
    for (int mi = 0; mi < 4; ++mi) {
        #pragma unroll
        for (int p = 0; p < 2; ++p) {
            int o = obase + 8*mi + 2*q + p;
            float ba = bias[o], bb = bias[512 + o];
            float* orow = out + ((size_t)b * cH + o) * cL + l0 + 64*wn + lm;
            #pragma unroll
            for (int ni = 0; ni < 4; ++ni) {
                float av = acc[mi][ni][2*p]     + ba;
                float gv = acc[mi][ni][2*p + 1] + bb;
                orow[16 * ni] = av / (1.f + expf(-gv));
            }
        }
    }
}

extern "C" void kernel_launch(void* const* d_in, const int* in_sizes, int n_in,
                              void* d_out, int out_size, void* d_ws, size_t ws_size,
                              hipStream_t stream)
{
    (void)in_sizes; (void)n_in; (void)out_size; (void)ws_size;
    const float* u          = (const float*)d_in[0];
    const float* log_dt     = (const float*)d_in[1];
    const float* log_A_real = (const float*)d_in[2];
    const float* A_imag     = (const float*)d_in[3];
    const float* C          = (const float*)d_in[4];
    const float* D          = (const float*)d_in[5];
    const float* W          = (const float*)d_in[6];
    const float* bias       = (const float*)d_in[7];
    float* out = (float*)d_out;
    float* ws  = (float*)d_ws;
    ushort* wsu = (ushort*)d_ws;
    ushort* Wp  = wsu + 2*OF_WP;
    ushort* gbf = wsu + 2*OF_G;
    ushort* gTu = wsu + 2*OF_GT;   // aliases A+V (dead after k_conv)

    hipLaunchKernelGGL(k_consts_vmat, dim3(cHN/256), dim3(256), 0, stream,
                       log_dt, log_A_real, A_imag, C, ws, wsu);
    hipLaunchKernelGGL(k_pack_w, dim3(1024*512/4/256), dim3(256), 0, stream, W, Wp);
    hipLaunchKernelGGL(k_embt, dim3(512*128/256), dim3(256), 0, stream, ws, D, wsu);
    hipLaunchKernelGGL(k_conv, dim3(512), dim3(512), 0, stream, u, ws, wsu, gbf);
    hipLaunchKernelGGL(k_transpose, dim3(cL/64, cH/64, cB), dim3(256), 0, stream, gbf, gTu);
    hipLaunchKernelGGL(k_gemm2, dim3(cL/128, 1024/128, cB), dim3(256), 0, stream,
                       Wp, bias, gTu, out);
}

// Round 7
// 263.077 us; speedup vs baseline: 1.1057x; 1.0157x over previous
//
#include <hip/hip_runtime.h>
#include <math.h>

// Problem dims (fixed by reference)
constexpr int cB = 8, cH = 512, cL = 4096, cN = 32;
constexpr int cG = 32, cLC = 128;            // 32 chunks of 128 along L
constexpr int cHN = cH * cN;                 // 16384

// Workspace layout (float offsets)
constexpr size_t OF_RR  = 0;
constexpr size_t OF_RI  = (size_t)cHN;
constexpr size_t OF_RPR = (size_t)2*cHN;     // r^128
constexpr size_t OF_RPI = (size_t)3*cHN;
constexpr size_t OF_C2R = (size_t)4*cHN;     // 2*Cs
constexpr size_t OF_C2I = (size_t)5*cHN;
constexpr size_t OF_DR  = (size_t)6*cHN;     // dt*Ar
constexpr size_t OF_DI  = (size_t)7*cHN;     // dt*Ai
constexpr size_t OF_K   = (size_t)8*cHN;                  // (unused; layout stability)
constexpr size_t OF_WP  = OF_K + (size_t)512*128;         // bf16 W packed: 1024*512 ush
constexpr size_t OF_A   = OF_WP + (size_t)1024*512/2;     // bf16 A=[T|Er|-Ei]: [512][128][192] ush
constexpr size_t OF_V   = OF_A + (size_t)512*128*192/2;   // bf16 V: [512][64][128] ush
constexpr size_t OF_XP  = OF_V + (size_t)512*64*128/2;    // (unused; layout stability)
constexpr size_t OF_G   = OF_XP + (size_t)512*256*64/2;   // bf16 g: [B][H][L] ush
// gT (bf16 [B][L][H] = 33.55 MB) ALIASES [OF_A, OF_XP) (dead after k_conv).
constexpr size_t OF_GT  = OF_A;
// end = OF_G + 8388608 = 21,430,272 floats = 85.7 MB (unchanged)

typedef __bf16 bf16x8 __attribute__((ext_vector_type(8)));
typedef float  f32x4  __attribute__((ext_vector_type(4)));

static __device__ __forceinline__ ushort f2bf(float x) {
    unsigned u = __float_as_uint(x);
    unsigned r = (u + 0x7fffu + ((u >> 16) & 1u)) >> 16;   // RNE
    return (ushort)r;
}
static __device__ __forceinline__ float bf2f(ushort v) {
    return __uint_as_float(((unsigned)v) << 16);
}
static __device__ __forceinline__ unsigned pk2(float a, float b) {
    return (unsigned)f2bf(a) | ((unsigned)f2bf(b) << 16);
}
static __device__ __forceinline__ float gelu(float v) {
    return 0.5f * v * (1.0f + erff(v * 0.70710678118654752f));
}
static __device__ __forceinline__ void gload16(const void* g, void* l) {
    __builtin_amdgcn_global_load_lds(
        (const __attribute__((address_space(1))) unsigned*)g,
        (__attribute__((address_space(3))) unsigned*)l, 16, 0, 0);
}

// ---------------- K0: per-(h,n) constants + V matrix (fused) ----------------
__global__ void k_consts_vmat(const float* __restrict__ log_dt,
                              const float* __restrict__ log_A_real,
                              const float* __restrict__ A_imag,
                              const float* __restrict__ Cin,
                              float* __restrict__ ws,
                              ushort* __restrict__ wsu)
{
    int tid = blockIdx.x * 256 + threadIdx.x;
    if (tid >= cHN) return;
    int h = tid >> 5, n = tid & 31;
    float dt = expf(log_dt[h]);
    float Ar = -expf(log_A_real[tid]);
    float Ai = A_imag[tid];
    float dr = dt * Ar, di = dt * Ai;
    float er = expf(dr);
    float rr = er * cosf(di), ri = er * sinf(di);
    float erL = expf(dr * (float)cLC);
    float diL = di * (float)cLC;
    float rpr = erL * cosf(diL), rpi = erL * sinf(diL);
    float cr = Cin[2*tid], ci = Cin[2*tid+1];
    float nr = rr - 1.0f, ni = ri;
    float inv = 1.0f / (Ar*Ar + Ai*Ai);
    float wr = (nr*Ar + ni*Ai) * inv;
    float wi = (ni*Ar - nr*Ai) * inv;
    float csr = cr*wr - ci*wi;
    float csi = cr*wi + ci*wr;
    ws[OF_RR  + tid] = rr;  ws[OF_RI  + tid] = ri;
    ws[OF_RPR + tid] = rpr; ws[OF_RPI + tid] = rpi;
    ws[OF_C2R + tid] = 2.0f*csr; ws[OF_C2I + tid] = 2.0f*csi;
    ws[OF_DR  + tid] = dr;  ws[OF_DI  + tid] = di;

    // --- vmat body (fused): powers r^(127-j) ---
    float e127 = expf(dr * 127.f), a127 = di * 127.f;
    float pr = e127 * cosf(a127), pi_ = e127 * sinf(a127);
    float rie = expf(-dr);
    float rc = rie * cosf(di), rs = -rie * sinf(di);
    ushort* vre = wsu + 2*OF_V + ((size_t)h*64 + n) * 128;
    ushort* vim = wsu + 2*OF_V + ((size_t)h*64 + 32 + n) * 128;
    for (int j4 = 0; j4 < 128; j4 += 4) {
        ushort4 r4, i4;
        #pragma unroll
        for (int e = 0; e < 4; ++e) {
            ((ushort*)&r4)[e] = f2bf(pr);
            ((ushort*)&i4)[e] = f2bf(pi_);
            float npr = pr*rc - pi_*rs;
            float npi = pr*rs + pi_*rc;
            pr = npr; pi_ = npi;
        }
        *(ushort4*)&vre[j4] = r4;
        *(ushort4*)&vim[j4] = i4;
    }
}

// ---------------- K0b: pack W -> bf16 with GLU row interleave ----------------
__global__ void k_pack_w(const float* __restrict__ W, ushort* __restrict__ Wp)
{
    int idx = blockIdx.x * 256 + threadIdx.x;
    int base = idx * 4;
    int m = base >> 9;
    int k = base & 511;
    int src = (m & 1) ? (512 + (m >> 1)) : (m >> 1);
    float4 v = *(const float4*)&W[(size_t)src * 512 + k];
    ushort4 o;
    o.x = f2bf(v.x); o.y = f2bf(v.y); o.z = f2bf(v.z); o.w = f2bf(v.w);
    *(ushort4*)&Wp[base] = o;
}

// ---------------- E matrix + k vector + Toeplitz fill (fused via LDS) ----------------
__global__ void k_embt(const float* __restrict__ ws, const float* __restrict__ Dvec,
                       ushort* __restrict__ wsu)
{
    __shared__ float kv[256];
    int t = threadIdx.x;
    int tid = blockIdx.x * 256 + t;             // 65536
    int h = tid >> 7, l = tid & 127;
    float fl = (float)l, fl1 = (float)(l + 1);
    const float* dr_ = ws + OF_DR + (size_t)h*32;
    const float* di_ = ws + OF_DI + (size_t)h*32;
    const float* c2r_ = ws + OF_C2R + (size_t)h*32;
    const float* c2i_ = ws + OF_C2I + (size_t)h*32;
    ushort* rowA = wsu + 2*OF_A + ((size_t)h*128 + l) * 192;
    float kacc = 0.f;
    for (int n4 = 0; n4 < 32; n4 += 4) {
        ushort4 prq, npq;
        #pragma unroll
        for (int e = 0; e < 4; ++e) {
            int n = n4 + e;
            float dr = dr_[n], di = di_[n], c2r = c2r_[n], c2i = c2i_[n];
            float e0 = expf(dr * fl), a0 = di * fl;
            float c0 = cosf(a0), s0 = sinf(a0);
            kacc += e0 * (c2r*c0 - c2i*s0);
            float e1 = expf(dr * fl1), a1 = di * fl1;
            float c1 = cosf(a1), s1 = sinf(a1);
            ((ushort*)&prq)[e] = f2bf(e1 * (c2r*c1 - c2i*s1));
            ((ushort*)&npq)[e] = f2bf(-e1 * (c2r*s1 + c2i*c1));
        }
        *(ushort4*)&rowA[128 + n4] = prq;
        *(ushort4*)&rowA[160 + n4] = npq;
    }
    kv[t] = kacc;
    __syncthreads();
    const float* krow = kv + ((t >> 7) << 7);
    float Dh = Dvec[h];
    for (int j8 = 0; j8 < 128; j8 += 8) {
        uint4 q;
        unsigned w[4];
        #pragma unroll
        for (int p = 0; p < 4; ++p) {
            int j0 = j8 + 2*p, j1 = j0 + 1;
            float v0 = (j0 <= l) ? krow[l - j0] : 0.f;
            float v1 = (j1 <= l) ? krow[l - j1] : 0.f;
            if (j0 == l) v0 += Dh;
            if (j1 == l) v1 += Dh;
            w[p] = pk2(v0, v1);
        }
        q.x = w[0]; q.y = w[1]; q.z = w[2]; q.w = w[3];
        *(uint4*)&rowA[j8] = q;
    }
}

// ---------------- Conv mega-kernel v2: 1024 threads, coalesced epilogue ----------------
// One block per h. Phases:
//  1: stage u->bf16 into Bs[gc][0..127]; V (64x128) into As rows 0..63;
//     A-matrix -> regs (T14 async-split).
//  2: state GEMM S[comp][gc] = V·u -> Bs[gc][128+comp]  (16 waves, 16 gc each).
//  3: chunk-scan in LDS (t<256) ; ds_write A-matrix (overwrites V).
//  4: main GEMM C[l][gc] = A·B (16 waves as 2M x 8N, 48 MFMA/wave).
//  5: gelu -> Os[gc][l] LDS overlay -> coalesced 256B-row stores of g.
// 16 waves/CU (vs 8) halves per-wave serial chains; LDS-bounced epilogue
// removes the 8B-scatter write amplification (WRITE 57->~34 MB).
__global__ __launch_bounds__(1024) void k_conv(const float* __restrict__ u,
                                               const float* __restrict__ ws,
                                               const ushort* __restrict__ wsu,
                                               ushort* __restrict__ g)
{
    __shared__ ushort sh[76800];            // 153600 B
    ushort* As = sh;                        // [128][200]: V rows 0..63, then A-matrix
    ushort* Bs = sh + 25600;                // [256][200]: [u_bf 0..127 | states 128..191]
    ushort* Os = sh;                        // [256][136] output overlay (As/Bs dead)

    const int t = threadIdx.x;
    const int h = blockIdx.x;
    const int wave = t >> 6, lane = t & 63;
    const int lm = lane & 15, q = lane >> 4;

    // --- A-matrix global loads into regs early; ds_write deferred to phase 3 ---
    uint4 areg[3];
    const int arow = t >> 3, ac0 = (t & 7) * 24;
    {
        const ushort* Ab = wsu + 2*OF_A + ((size_t)h*128 + arow) * 192 + ac0;
        #pragma unroll
        for (int e = 0; e < 3; ++e) areg[e] = *(const uint4*)&Ab[8*e];
    }
    // --- stage V[h]: 64x128 bf16 into As rows 0..63 (1 uint4/thread) ---
    {
        const int vrow = t >> 4, vc0 = (t & 15) * 8;
        *(uint4*)&As[vrow*200 + vc0] =
            *(const uint4*)(wsu + 2*OF_V + ((size_t)h*64 + vrow) * 128 + vc0);
    }
    // --- stage u (fp32 -> bf16): 4 threads/gc, 32 elems each ---
    {
        const int gc = t >> 2, qt = t & 3;
        const int ub = gc >> 5, uc = gc & 31;
        const float* up = u + ((size_t)(ub*cH + h)) * cL + (size_t)uc*128 + qt*32;
        ushort* d = &Bs[gc * 200 + qt*32];
        #pragma unroll
        for (int e = 0; e < 4; ++e) {
            float4 f0 = *(const float4*)&up[8*e];
            float4 f1 = *(const float4*)&up[8*e + 4];
            uint4 w;
            w.x = pk2(f0.x, f0.y); w.y = pk2(f0.z, f0.w);
            w.z = pk2(f1.x, f1.y); w.w = pk2(f1.z, f1.w);
            *(uint4*)&d[8*e] = w;
        }
    }
    __syncthreads();

    // --- phase 2: state GEMM. Wave -> 16 gc cols (one MFMA tile), all 64 comps ---
    {
        f32x4 accs[4];
        #pragma unroll
        for (int i = 0; i < 4; ++i) accs[i] = (f32x4){0.f,0.f,0.f,0.f};
        #pragma unroll
        for (int j0 = 0; j0 < 128; j0 += 32) {
            bf16x8 vf[4], uf;
            #pragma unroll
            for (int mi = 0; mi < 4; ++mi)
                vf[mi] = *(const bf16x8*)&As[(16*mi + lm) * 200 + j0 + 8*q];
            uf = *(const bf16x8*)&Bs[(16*wave + lm) * 200 + j0 + 8*q];
            #pragma unroll
            for (int mi = 0; mi < 4; ++mi)
                accs[mi] = __builtin_amdgcn_mfma_f32_16x16x32_bf16(vf[mi], uf, accs[mi], 0,0,0);
        }
        const int col = 16*wave + lm;
        #pragma unroll
        for (int mi = 0; mi < 4; ++mi) {
            ushort4 st;
            st.x = f2bf(accs[mi][0]); st.y = f2bf(accs[mi][1]);
            st.z = f2bf(accs[mi][2]); st.w = f2bf(accs[mi][3]);
            *(ushort4*)&Bs[col*200 + 128 + 16*mi + 4*q] = st;
        }
    }
    __syncthreads();

    // --- phase 3a: chunk scan (thread (b,n) walks 32 chunks in LDS) ---
    if (t < 256) {
        const int sb = t >> 5, sn = t & 31;
        float rpr = ws[OF_RPR + (size_t)h*32 + sn];
        float rpi = ws[OF_RPI + (size_t)h*32 + sn];
        float Xr = 0.f, Xi = 0.f;
        ushort* p = &Bs[(sb*32) * 200 + 128 + sn];
        #pragma unroll 4
        for (int c = 0; c < cG; ++c, p += 200) {
            float sr = bf2f(p[0]), si = bf2f(p[32]);
            p[0]  = f2bf(Xr);
            p[32] = f2bf(Xi);
            float nXr = fmaf(rpr, Xr, fmaf(-rpi, Xi, sr));
            float nXi = fmaf(rpr, Xi, fmaf(rpi, Xr, si));
            Xr = nXr; Xi = nXi;
        }
    }
    // --- phase 3b: ds_write A-matrix from regs (overwrites V) ---
    {
        ushort* d = &As[arow*200 + ac0];
        #pragma unroll
        for (int e = 0; e < 3; ++e) *(uint4*)&d[8*e] = areg[e];
    }
    __syncthreads();

    // --- phase 4: main GEMM. 16 waves = 2(M:64 rows) x 8(N:32 gc) ---
    const int wm = wave & 1, wn = wave >> 1;
    f32x4 acc[4][2];
    #pragma unroll
    for (int i = 0; i < 4; ++i)
        #pragma unroll
        for (int j = 0; j < 2; ++j) acc[i][j] = (f32x4){0.f,0.f,0.f,0.f};

    #pragma unroll
    for (int k0 = 0; k0 < 192; k0 += 32) {
        // lower-triangular skip: rows 0..63 x k 64..127 are all zero
        if ((wm == 0) && (k0 == 64 || k0 == 96)) continue;
        bf16x8 af[4], bfr[2];
        #pragma unroll
        for (int mi = 0; mi < 4; ++mi)
            af[mi] = *(const bf16x8*)&As[(64*wm + 16*mi + lm) * 200 + k0 + 8*q];
        #pragma unroll
        for (int ni = 0; ni < 2; ++ni)
            bfr[ni] = *(const bf16x8*)&Bs[(32*wn + 16*ni + lm) * 200 + k0 + 8*q];
        #pragma unroll
        for (int mi = 0; mi < 4; ++mi)
            #pragma unroll
            for (int ni = 0; ni < 2; ++ni)
                acc[mi][ni] = __builtin_amdgcn_mfma_f32_16x16x32_bf16(af[mi], bfr[ni], acc[mi][ni], 0,0,0);
    }
    __syncthreads();   // all As/Bs reads done before Os overlay writes

    // --- phase 5a: gelu -> Os[gc][l] ---
    #pragma unroll
    for (int ni = 0; ni < 2; ++ni) {
        int gc = 32*wn + 16*ni + lm;
        #pragma unroll
        for (int mi = 0; mi < 4; ++mi) {
            int l = 64*wm + 16*mi + 4*q;
            ushort4 st;
            st.x = f2bf(gelu(acc[mi][ni][0]));
            st.y = f2bf(gelu(acc[mi][ni][1]));
            st.z = f2bf(gelu(acc[mi][ni][2]));
            st.w = f2bf(gelu(acc[mi][ni][3]));
            *(ushort4*)&Os[gc*136 + l] = st;
        }
    }
    __syncthreads();
    // --- phase 5b: coalesced store: 4 threads stream one 256B row of g ---
    {
        const int gc = t >> 2, qt = t & 3;
        const int ob = gc >> 5, oc = gc & 31;
        ushort* grow = g + ((size_t)(ob*cH + h)) * cL + (size_t)oc*128 + qt*32;
        const ushort* s = &Os[gc*136 + qt*32];
        #pragma unroll
        for (int e = 0; e < 4; ++e)
            *(uint4*)&grow[8*e] = *(const uint4*)&s[8*e];
    }
}

// ---------------- transpose g[b][h][l] -> gT[b][l][h] (bf16) ----------------
__global__ __launch_bounds__(256) void k_transpose(const ushort* __restrict__ gsrc,
                                                   ushort* __restrict__ gT)
{
    __shared__ ushort tile[64 * 64];
    const int t = threadIdx.x;
    const int b  = blockIdx.z;
    const int h0 = blockIdx.y << 6;
    const int l0 = blockIdx.x << 6;
    const ushort* gb = gsrc + ((size_t)b * cH + h0) * cL + l0;
    const int lb = t & 7;
    #pragma unroll
    for (int half = 0; half < 2; ++half) {
        int r = (t >> 3) + half * 32;
        uint4 v = *(const uint4*)&gb[(size_t)r * cL + lb * 8];
        int sb = lb ^ (r & 7) ^ (r >> 3);
        *(uint4*)&tile[r * 64 + sb * 8] = v;
    }
    __syncthreads();
    ushort* gTb = gT + ((size_t)b * cL + l0) * cH + h0;
    #pragma unroll
    for (int half = 0; half < 2; ++half) {
        int l  = (t >> 3) + half * 32;
        int hb = t & 7;
        ushort vals[8];
        #pragma unroll
        for (int e = 0; e < 8; ++e) {
            int r  = hb * 8 + e;
            int sb = (l >> 3) ^ (r & 7) ^ (r >> 3);
            vals[e] = tile[r * 64 + sb * 8 + (l & 7)];
        }
        *(uint4*)&gTb[(size_t)l * cH + hb * 8] = *(uint4*)vals;
    }
}

// ---------------- K4: B^T GEMM, 2-buffer m97 structure (R1 winner) ----------------
__global__ __launch_bounds__(256) void k_gemm2(const ushort* __restrict__ Wp,
                                               const float* __restrict__ bias,
                                               const ushort* __restrict__ gT,
                                               float* __restrict__ out)
{
    __shared__ ushort As[2][128 * 32];
    __shared__ ushort Bs[2][128 * 32];
    const int t    = threadIdx.x;
    const int l0   = blockIdx.x * 128;
    const int by   = blockIdx.y;
    const int b    = blockIdx.z;
    const int wave = t >> 6, lane = t & 63;
    const int wm   = wave & 1, wn = wave >> 1;
    const int lm   = lane & 15, q = lane >> 4;

    const int srow = lane >> 2;              // row within 16-row chunk
    const int scol = (lane & 3) * 8;         // ushort offset within 64-B row
    const ushort* Ag = Wp + (size_t)(by * 128) * 512;
    const ushort* Bg = gT + ((size_t)b * cL + l0) * 512;

    f32x4 acc[4][4];
    #pragma unroll
    for (int i = 0; i < 4; ++i)
        #pragma unroll
        for (int j = 0; j < 4; ++j)
            acc[i][j] = (f32x4){0.f, 0.f, 0.f, 0.f};

    auto stage = [&](ushort* Asb, ushort* Bsb, int k0) {
        #pragma unroll
        for (int j = 0; j < 2; ++j) {
            int row = 32*wave + 16*j + srow;
            gload16(Ag + (size_t)row * 512 + k0 + scol,
                    (char*)Asb + wave*2048 + j*1024);
            gload16(Bg + (size_t)row * 512 + k0 + scol,
                    (char*)Bsb + wave*2048 + j*1024);
        }
    };
    auto compute = [&](const ushort* Asb, const ushort* Bsb) {
        bf16x8 af[4], bfr[4];
        #pragma unroll
        for (int mi = 0; mi < 4; ++mi)
            af[mi] = *(const bf16x8*)&Asb[(64*wm + 16*mi + lm) * 32 + 8*q];
        #pragma unroll
        for (int ni = 0; ni < 4; ++ni)
            bfr[ni] = *(const bf16x8*)&Bsb[(64*wn + 16*ni + lm) * 32 + 8*q];
        #pragma unroll
        for (int mi = 0; mi < 4; ++mi)
            #pragma unroll
            for (int ni = 0; ni < 4; ++ni)
                acc[mi][ni] = __builtin_amdgcn_mfma_f32_16x16x32_bf16(af[mi], bfr[ni], acc[mi][ni], 0,0,0);
    };

    stage(As[0], Bs[0], 0);
    __syncthreads();                         // drains vmcnt(0) -> buf0 ready
    int cur = 0;
    for (int ks = 0; ks < 15; ++ks) {
        stage(As[cur ^ 1], Bs[cur ^ 1], (ks + 1) * 32);   // prefetch next tile
        compute(As[cur], Bs[cur]);                         // MFMA current tile
        __syncthreads();                                   // drain prefetch + sync
        cur ^= 1;
    }
    compute(As[cur], Bs[cur]);

    // epilogue: bias + GLU
    const int obase = by * 64 + 32 * wm;
    #pragma unroll
    for (int mi = 0; mi < 4; ++mi) {
        #pragma unroll
        for (int p = 0; p < 2; ++p) {
            int o = obase + 8*mi + 2*q + p;
            float ba = bias[o], bb = bias[512 + o];
            float* orow = out + ((size_t)b * cH + o) * cL + l0 + 64*wn + lm;
            #pragma unroll
            for (int ni = 0; ni < 4; ++ni) {
                float av = acc[mi][ni][2*p]     + ba;
                float gv = acc[mi][ni][2*p + 1] + bb;
                orow[16 * ni] = av / (1.f + expf(-gv));
            }
        }
    }
}

extern "C" void kernel_launch(void* const* d_in, const int* in_sizes, int n_in,
                              void* d_out, int out_size, void* d_ws, size_t ws_size,
                              hipStream_t stream)
{
    (void)in_sizes; (void)n_in; (void)out_size; (void)ws_size;
    const float* u          = (const float*)d_in[0];
    const float* log_dt     = (const float*)d_in[1];
    const float* log_A_real = (const float*)d_in[2];
    const float* A_imag     = (const float*)d_in[3];
    const float* C          = (const float*)d_in[4];
    const float* D          = (const float*)d_in[5];
    const float* W          = (const float*)d_in[6];
    const float* bias       = (const float*)d_in[7];
    float* out = (float*)d_out;
    float* ws  = (float*)d_ws;
    ushort* wsu = (ushort*)d_ws;
    ushort* Wp  = wsu + 2*OF_WP;
    ushort* gbf = wsu + 2*OF_G;
    ushort* gTu = wsu + 2*OF_GT;   // aliases A+V (dead after k_conv)

    hipLaunchKernelGGL(k_consts_vmat, dim3(cHN/256), dim3(256), 0, stream,
                       log_dt, log_A_real, A_imag, C, ws, wsu);
    hipLaunchKernelGGL(k_pack_w, dim3(1024*512/4/256), dim3(256), 0, stream, W, Wp);
    hipLaunchKernelGGL(k_embt, dim3(512*128/256), dim3(256), 0, stream, ws, D, wsu);
    hipLaunchKernelGGL(k_conv, dim3(512), dim3(1024), 0, stream, u, ws, wsu, gbf);
    hipLaunchKernelGGL(k_transpose, dim3(cL/64, cH/64, cB), dim3(256), 0, stream, gbf, gTu);
    hipLaunchKernelGGL(k_gemm2, dim3(cL/128, 1024/128, cB), dim3(256), 0, stream,
                       Wp, bias, gTu, out);
}